// Round 4
// baseline (430.755 us; speedup 1.0000x reference)
//
#include <hip/hip_runtime.h>
#include <hip/hip_fp16.h>

#define RES 256
#define FEAT 32
#define PLANE_ELEMS (FEAT * RES * RES)   // 2097152, fp16 plane = 4 MB
#define NBINS 32768                      // 32^3 Morton bins

// ---------------- preprocessing ----------------

// Transpose+quantize all 3 planes (C,H,W) fp32 -> (H,W,C) fp16.
// Thread t -> (pl, y, x, cg): reads 8 floats (channels cg*8..cg*8+7) at (y,x),
// writes one uint4 (8 halves). Wave reads full 64B lines; writes 4KB contiguous.
__global__ __launch_bounds__(256) void transpose_quant(const float* __restrict__ p0,
                                                       const float* __restrict__ p1,
                                                       const float* __restrict__ p2,
                                                       __half* __restrict__ outp) {
    int t = blockIdx.x * 256 + threadIdx.x;          // t < 3 * 262144
    int pl = t >> 18;
    int r = t & 262143;
    int cg = r & 3;
    int x = (r >> 2) & 255;
    int y = r >> 10;
    const float* in = (pl == 0 ? p0 : (pl == 1 ? p1 : p2)) + y * 256 + x;
    union { __half h[8]; uint4 v; } u;
#pragma unroll
    for (int k = 0; k < 8; ++k)
        u.h[k] = __float2half(in[(size_t)(cg * 8 + k) * 65536]);
    reinterpret_cast<uint4*>(outp)[((size_t)pl << 18) | ((size_t)((y << 8) | x) << 2) | cg] = u.v;
}

__device__ inline unsigned spread3(unsigned v) {
    unsigned r = 0;
    r |= (v & 1u);
    r |= (v & 2u) << 2;
    r |= (v & 4u) << 4;
    r |= (v & 8u) << 6;
    r |= (v & 16u) << 8;
    return r;
}

__global__ __launch_bounds__(256) void build_hist_keys(const float* __restrict__ pts,
                                                       const float* __restrict__ aabb,
                                                       int* __restrict__ hist,
                                                       int* __restrict__ keys, int n) {
    int i = blockIdx.x * 256 + threadIdx.x;
    if (i >= n) return;
    float a00 = aabb[0], a01 = aabb[1], a02 = aabb[2];
    float a10 = aabb[3], a11 = aabb[4], a12 = aabb[5];
    float px = (pts[i * 3 + 0] - a00) * (2.0f / (a10 - a00)) - 1.0f;
    float py = (pts[i * 3 + 1] - a01) * (2.0f / (a11 - a01)) - 1.0f;
    float pz = (pts[i * 3 + 2] - a02) * (2.0f / (a12 - a02)) - 1.0f;
    unsigned ux = (unsigned)min(max((int)((px + 1.0f) * 16.0f), 0), 31);
    unsigned uy = (unsigned)min(max((int)((py + 1.0f) * 16.0f), 0), 31);
    unsigned uz = (unsigned)min(max((int)((pz + 1.0f) * 16.0f), 0), 31);
    int key = (int)(spread3(ux) | (spread3(uy) << 1) | (spread3(uz) << 2));
    keys[i] = key;
    atomicAdd(&hist[key], 1);
}

__global__ __launch_bounds__(1024) void scan_hist(int* __restrict__ hist) {
    __shared__ int sums[1024];
    int t = threadIdx.x;
    int base = t * 32;
    int local[32];
    int s = 0;
#pragma unroll
    for (int i = 0; i < 32; ++i) { local[i] = hist[base + i]; s += local[i]; }
    sums[t] = s;
    __syncthreads();
    for (int off = 1; off < 1024; off <<= 1) {
        int v = 0;
        if (t >= off) v = sums[t - off];
        __syncthreads();
        if (t >= off) sums[t] += v;
        __syncthreads();
    }
    int excl = (t == 0) ? 0 : sums[t - 1];
#pragma unroll
    for (int i = 0; i < 32; ++i) { hist[base + i] = excl; excl += local[i]; }
}

// Scatter sorted, pre-transformed records: [cx,cy,cz,0, hx,hy,hz,0] in pixel units.
__global__ __launch_bounds__(256) void scatter_pack(const float* __restrict__ pts,
                                                    const float* __restrict__ scales,
                                                    const float* __restrict__ aabb,
                                                    const int* __restrict__ keys,
                                                    int* __restrict__ hist,
                                                    float* __restrict__ ppk,
                                                    int* __restrict__ idx_s, int n) {
    int i = blockIdx.x * 256 + threadIdx.x;
    if (i >= n) return;
    float a00 = aabb[0], a01 = aabb[1], a02 = aabb[2];
    float a10 = aabb[3], a11 = aabb[4], a12 = aabb[5];
    float px = (pts[i * 3 + 0] - a00) * (2.0f / (a10 - a00)) - 1.0f;
    float py = (pts[i * 3 + 1] - a01) * (2.0f / (a11 - a01)) - 1.0f;
    float pz = (pts[i * 3 + 2] - a02) * (2.0f / (a12 - a02)) - 1.0f;
    int pos = atomicAdd(&hist[keys[i]], 1);
    float4* o = reinterpret_cast<float4*>(ppk) + (size_t)pos * 2;
    o[0] = make_float4((px + 1.0f) * 127.5f, (py + 1.0f) * 127.5f, (pz + 1.0f) * 127.5f, 0.0f);
    o[1] = make_float4(scales[i * 3 + 0] * 63.75f, scales[i * 3 + 1] * 63.75f,
                       scales[i * 3 + 2] * 63.75f, 0.0f);
    idx_s[pos] = i;
}

// ---------------- main kernel ----------------

// 16 fp16 channels MAC'd into 16 fp32 accumulators with forced v_fma_mix_f32.
__device__ __forceinline__ void corner16(float fs[16], const char* __restrict__ p, float w) {
    uint4 r0 = *reinterpret_cast<const uint4*>(p);
    uint4 r1 = *reinterpret_cast<const uint4*>(p + 16);
    unsigned u[8] = {r0.x, r0.y, r0.z, r0.w, r1.x, r1.y, r1.z, r1.w};
#pragma unroll
    for (int i = 0; i < 8; ++i) {
        asm("v_fma_mix_f32 %0, %1, %2, %0 op_sel_hi:[1,0,0]"
            : "+v"(fs[2 * i]) : "v"(u[i]), "v"(w));
        asm("v_fma_mix_f32 %0, %1, %2, %0 op_sel:[1,0,0] op_sel_hi:[1,0,0]"
            : "+v"(fs[2 * i + 1]) : "v"(u[i]), "v"(w));
    }
}

__device__ __forceinline__ void pair_accum16(float interp[16], const __half* __restrict__ plane,
                                             float cx, float cy, float hx, float hy, int chan) {
    const int SI[13] = {2, 0, 1, 3, 4, 2, 2, 2, 2, 3, 3, 1, 1};
    const int SJ[13] = {2, 2, 2, 2, 2, 0, 1, 3, 4, 3, 1, 3, 1};

    float wx[5], wy[5];
    int colA[5], colB[5], rowA[5], rowB[5];
    float hx2 = hx + hx, hy2 = hy + hy;
    float xs[5] = {cx - hx2, cx - hx, cx, cx + hx, cx + hx2};
    float ys[5] = {cy - hy2, cy - hy, cy, cy + hy, cy + hy2};
    int colMax = 255 * 64 + chan;
#pragma unroll
    for (int k = 0; k < 5; ++k) {
        float x = fminf(fmaxf(xs[k], 0.0f), 255.0f);
        float xf = floorf(x);
        wx[k] = x - xf;
        colA[k] = (int)xf * 64 + chan;
        colB[k] = min(colA[k] + 64, colMax);
        float y = fminf(fmaxf(ys[k], 0.0f), 255.0f);
        float yf = floorf(y);
        wy[k] = y - yf;
        rowA[k] = (int)yf * (RES * 64);
        rowB[k] = min(rowA[k] + RES * 64, 255 * RES * 64);
    }

    float fs[16];
#pragma unroll
    for (int c = 0; c < 16; ++c) fs[c] = 0.0f;
    const char* base = reinterpret_cast<const char*>(plane);
#pragma unroll
    for (int s = 0; s < 13; ++s) {
        int i = SI[s], j = SJ[s];
        float wxi = wx[i], wyj = wy[j];
        float wxc = 1.0f - wxi, wyc = 1.0f - wyj;
        corner16(fs, base + (rowA[j] + colA[i]), wxc * wyc);
        corner16(fs, base + (rowA[j] + colB[i]), wxi * wyc);
        corner16(fs, base + (rowB[j] + colA[i]), wxc * wyj);
        corner16(fs, base + (rowB[j] + colB[i]), wxi * wyj);
    }
    const float inv13 = 1.0f / 13.0f;
#pragma unroll
    for (int c = 0; c < 16; ++c) interp[c] *= fs[c] * inv13;
}

// 2 lanes per point, 16 channels per lane.
__global__ __launch_bounds__(256) void wpf_main2(const float* __restrict__ ppk,
                                                 const int* __restrict__ idx_s,
                                                 const __half* __restrict__ planes, // 3 concat
                                                 float* __restrict__ out, int n, int swizzle) {
    int b = blockIdx.x;
    if (swizzle) {
        int nb = gridDim.x;
        int chunk = nb >> 3;
        b = (b & 7) * chunk + (b >> 3);
    }
    int t = b * 256 + threadIdx.x;
    int pt = t >> 1;
    int cg = t & 1;
    if (pt >= n) return;

    float4 a  = reinterpret_cast<const float4*>(ppk)[(size_t)pt * 2];
    float4 hh = reinterpret_cast<const float4*>(ppk)[(size_t)pt * 2 + 1];
    int chan = cg * 32;   // byte offset of this lane's 16 channels

    float interp[16];
#pragma unroll
    for (int c = 0; c < 16; ++c) interp[c] = 1.0f;

#pragma unroll 1
    for (int pr = 0; pr < 3; ++pr) {
        const __half* pl = planes + (size_t)pr * PLANE_ELEMS;
        float cx = (pr == 2) ? a.y : a.x;
        float cy = (pr == 0) ? a.y : a.z;
        float hx = (pr == 2) ? hh.y : hh.x;
        float hy = (pr == 0) ? hh.y : hh.z;
        pair_accum16(interp, pl, cx, cy, hx, hy, chan);
    }

    int oi = idx_s[pt];
    float4* o = reinterpret_cast<float4*>(out + (size_t)oi * 32 + cg * 16);
    o[0] = make_float4(interp[0], interp[1], interp[2], interp[3]);
    o[1] = make_float4(interp[4], interp[5], interp[6], interp[7]);
    o[2] = make_float4(interp[8], interp[9], interp[10], interp[11]);
    o[3] = make_float4(interp[12], interp[13], interp[14], interp[15]);
}

// ---------------- fallback (ws too small): direct fp32 strided path ----------------
__global__ __launch_bounds__(256) void wpf_plain(const float* __restrict__ pts,
                                                 const float* __restrict__ scales,
                                                 const float* __restrict__ p0,
                                                 const float* __restrict__ p1,
                                                 const float* __restrict__ p2,
                                                 const float* __restrict__ aabb,
                                                 float* __restrict__ out, int n) {
    const float offx[13] = {0.f, -1.f, -0.5f, 0.5f, 1.f, 0.f, 0.f, 0.f, 0.f, 0.5f, 0.5f, -0.5f, -0.5f};
    const float offy[13] = {0.f, 0.f, 0.f, 0.f, 0.f, -1.f, -0.5f, 0.5f, 1.f, 0.5f, -0.5f, 0.5f, -0.5f};
    int t = blockIdx.x * 256 + threadIdx.x;
    int pt = t >> 3;
    int cg = t & 7;
    if (pt >= n) return;
    float a00 = aabb[0], a01 = aabb[1], a02 = aabb[2];
    float a10 = aabb[3], a11 = aabb[4], a12 = aabb[5];
    float px = (pts[pt * 3 + 0] - a00) * (2.0f / (a10 - a00)) - 1.0f;
    float py = (pts[pt * 3 + 1] - a01) * (2.0f / (a11 - a01)) - 1.0f;
    float pz = (pts[pt * 3 + 2] - a02) * (2.0f / (a12 - a02)) - 1.0f;
    float scx = scales[pt * 3 + 0], scy = scales[pt * 3 + 1], scz = scales[pt * 3 + 2];
    float4 interp = make_float4(1.f, 1.f, 1.f, 1.f);
    for (int pair = 0; pair < 3; ++pair) {
        const float* plane = pair == 0 ? p0 : (pair == 1 ? p1 : p2);
        float bx = pair == 2 ? py : px;
        float by = pair == 0 ? py : pz;
        float sx = pair == 2 ? scy : scx;
        float sy = pair == 0 ? scy : scz;
        float4 featsum = make_float4(0.f, 0.f, 0.f, 0.f);
        for (int s = 0; s < 13; ++s) {
            float x = fminf(fmaxf((bx + sx * offx[s] + 1.0f) * 127.5f, 0.0f), 255.0f);
            float y = fminf(fmaxf((by + sy * offy[s] + 1.0f) * 127.5f, 0.0f), 255.0f);
            float x0f = floorf(x), y0f = floorf(y);
            float wx = x - x0f, wy = y - y0f;
            int x0 = (int)x0f, y0 = (int)y0f;
            int x1 = min(x0 + 1, RES - 1), y1 = min(y0 + 1, RES - 1);
            float w00 = (1.0f - wx) * (1.0f - wy), w10 = wx * (1.0f - wy);
            float w01 = (1.0f - wx) * wy, w11 = wx * wy;
            int c0 = cg << 2;
            for (int c = 0; c < 4; ++c) {
                const float* pl = plane + (size_t)(c0 + c) * (RES * RES);
                float f = pl[y0 * RES + x0] * w00 + pl[y0 * RES + x1] * w10 +
                          pl[y1 * RES + x0] * w01 + pl[y1 * RES + x1] * w11;
                (&featsum.x)[c] += f;
            }
        }
        const float inv13 = 1.0f / 13.0f;
        interp.x *= featsum.x * inv13;
        interp.y *= featsum.y * inv13;
        interp.z *= featsum.z * inv13;
        interp.w *= featsum.w * inv13;
    }
    reinterpret_cast<float4*>(out)[(size_t)pt * 8 + cg] = interp;
}

extern "C" void kernel_launch(void* const* d_in, const int* in_sizes, int n_in,
                              void* d_out, int out_size, void* d_ws, size_t ws_size,
                              hipStream_t stream) {
    const float* pts    = (const float*)d_in[0];
    const float* scales = (const float*)d_in[2];
    const float* p0     = (const float*)d_in[3];
    const float* p1     = (const float*)d_in[4];
    const float* p2     = (const float*)d_in[5];
    const float* aabb   = (const float*)d_in[6];
    float* out = (float*)d_out;

    int n = in_sizes[0] / 3;
    int pt_blocks = (n + 255) / 256;

    size_t planes_hbytes = (size_t)3 * PLANE_ELEMS * sizeof(__half);  // 12 MB
    size_t ppk_bytes = (size_t)n * 8 * sizeof(float);                 // 16 MB
    size_t idx_bytes = (size_t)n * sizeof(int);
    size_t key_bytes = (size_t)n * sizeof(int);
    size_t hist_bytes = (size_t)NBINS * sizeof(int);
    size_t need = planes_hbytes + ppk_bytes + idx_bytes + key_bytes + hist_bytes;

    if (ws_size >= need) {
        __half* planes_h = (__half*)d_ws;
        float*  ppk   = (float*)((char*)d_ws + planes_hbytes);
        int*    idx_s = (int*)((char*)ppk + ppk_bytes);
        int*    keys  = idx_s + n;
        int*    hist  = keys + n;

        transpose_quant<<<(3 * 262144) / 256, 256, 0, stream>>>(p0, p1, p2, planes_h);
        hipMemsetAsync(hist, 0, hist_bytes, stream);
        build_hist_keys<<<pt_blocks, 256, 0, stream>>>(pts, aabb, hist, keys, n);
        scan_hist<<<1, 1024, 0, stream>>>(hist);
        scatter_pack<<<pt_blocks, 256, 0, stream>>>(pts, scales, aabb, keys, hist,
                                                    ppk, idx_s, n);
        int main_blocks = (n * 2 + 255) / 256;
        int swizzle = (main_blocks % 8 == 0) ? 1 : 0;
        wpf_main2<<<main_blocks, 256, 0, stream>>>(ppk, idx_s, planes_h, out, n, swizzle);
    } else {
        int main_blocks = (n * 8 + 255) / 256;
        wpf_plain<<<main_blocks, 256, 0, stream>>>(pts, scales, p0, p1, p2, aabb, out, n);
    }
}

// Round 5
// 406.157 us; speedup vs baseline: 1.0606x; 1.0606x over previous
//
#include <hip/hip_runtime.h>
#include <hip/hip_fp16.h>

#define RES 256
#define FEAT 32
#define PLANE_ELEMS (FEAT * RES * RES)   // 2097152, fp16 plane = 4 MB
#define NBINS 32768                      // 32^3 Morton bins
#define TQ_BLOCKS 3072                   // 3 * 262144 / 256

// ---------------- preprocessing ----------------

__device__ inline unsigned spread3(unsigned v) {
    unsigned r = 0;
    r |= (v & 1u);
    r |= (v & 2u) << 2;
    r |= (v & 4u) << 4;
    r |= (v & 8u) << 6;
    r |= (v & 16u) << 8;
    return r;
}

// Fused: [0, TQ_BLOCKS) transpose+quantize planes (C,H,W) fp32 -> (H,W,C) fp16;
// [TQ_BLOCKS, ...) Morton histogram + key store.
__global__ __launch_bounds__(256) void pre_fused(const float* __restrict__ p0,
                                                 const float* __restrict__ p1,
                                                 const float* __restrict__ p2,
                                                 __half* __restrict__ outp,
                                                 const float* __restrict__ pts,
                                                 const float* __restrict__ aabb,
                                                 int* __restrict__ hist,
                                                 int* __restrict__ keys, int n) {
    if (blockIdx.x < TQ_BLOCKS) {
        int t = blockIdx.x * 256 + threadIdx.x;      // t < 3 * 262144
        int pl = t >> 18;
        int r = t & 262143;
        int cg = r & 3;
        int x = (r >> 2) & 255;
        int y = r >> 10;
        const float* in = (pl == 0 ? p0 : (pl == 1 ? p1 : p2)) + y * 256 + x;
        union { __half h[8]; uint4 v; } u;
#pragma unroll
        for (int k = 0; k < 8; ++k)
            u.h[k] = __float2half(in[(size_t)(cg * 8 + k) * 65536]);
        reinterpret_cast<uint4*>(outp)[((size_t)pl << 18) | ((size_t)((y << 8) | x) << 2) | cg] = u.v;
    } else {
        int i = (blockIdx.x - TQ_BLOCKS) * 256 + threadIdx.x;
        if (i >= n) return;
        float a00 = aabb[0], a01 = aabb[1], a02 = aabb[2];
        float a10 = aabb[3], a11 = aabb[4], a12 = aabb[5];
        float px = (pts[i * 3 + 0] - a00) * (2.0f / (a10 - a00)) - 1.0f;
        float py = (pts[i * 3 + 1] - a01) * (2.0f / (a11 - a01)) - 1.0f;
        float pz = (pts[i * 3 + 2] - a02) * (2.0f / (a12 - a02)) - 1.0f;
        unsigned ux = (unsigned)min(max((int)((px + 1.0f) * 16.0f), 0), 31);
        unsigned uy = (unsigned)min(max((int)((py + 1.0f) * 16.0f), 0), 31);
        unsigned uz = (unsigned)min(max((int)((pz + 1.0f) * 16.0f), 0), 31);
        int key = (int)(spread3(ux) | (spread3(uy) << 1) | (spread3(uz) << 2));
        keys[i] = key;
        atomicAdd(&hist[key], 1);
    }
}

__global__ __launch_bounds__(1024) void scan_hist(int* __restrict__ hist) {
    __shared__ int sums[1024];
    int t = threadIdx.x;
    int base = t * 32;
    int local[32];
    int s = 0;
#pragma unroll
    for (int i = 0; i < 32; ++i) { local[i] = hist[base + i]; s += local[i]; }
    sums[t] = s;
    __syncthreads();
    for (int off = 1; off < 1024; off <<= 1) {
        int v = 0;
        if (t >= off) v = sums[t - off];
        __syncthreads();
        if (t >= off) sums[t] += v;
        __syncthreads();
    }
    int excl = (t == 0) ? 0 : sums[t - 1];
#pragma unroll
    for (int i = 0; i < 32; ++i) { hist[base + i] = excl; excl += local[i]; }
}

// Scatter sorted, pre-transformed records: [cx,cy,cz,0, hx,hy,hz,0] in pixel units.
__global__ __launch_bounds__(256) void scatter_pack(const float* __restrict__ pts,
                                                    const float* __restrict__ scales,
                                                    const float* __restrict__ aabb,
                                                    const int* __restrict__ keys,
                                                    int* __restrict__ hist,
                                                    float* __restrict__ ppk,
                                                    int* __restrict__ idx_s, int n) {
    int i = blockIdx.x * 256 + threadIdx.x;
    if (i >= n) return;
    float a00 = aabb[0], a01 = aabb[1], a02 = aabb[2];
    float a10 = aabb[3], a11 = aabb[4], a12 = aabb[5];
    float px = (pts[i * 3 + 0] - a00) * (2.0f / (a10 - a00)) - 1.0f;
    float py = (pts[i * 3 + 1] - a01) * (2.0f / (a11 - a01)) - 1.0f;
    float pz = (pts[i * 3 + 2] - a02) * (2.0f / (a12 - a02)) - 1.0f;
    int pos = atomicAdd(&hist[keys[i]], 1);
    float4* o = reinterpret_cast<float4*>(ppk) + (size_t)pos * 2;
    o[0] = make_float4((px + 1.0f) * 127.5f, (py + 1.0f) * 127.5f, (pz + 1.0f) * 127.5f, 0.0f);
    o[1] = make_float4(scales[i * 3 + 0] * 63.75f, scales[i * 3 + 1] * 63.75f,
                       scales[i * 3 + 2] * 63.75f, 0.0f);
    idx_s[pos] = i;
}

// ---------------- main kernel ----------------

// 8 fp16 channels MAC'd into 8 fp32 accumulators via one 16B load + 8 v_fma_mix_f32.
__device__ __forceinline__ void corner8(float fs[8], const char* __restrict__ p, float w) {
    uint4 r = *reinterpret_cast<const uint4*>(p);
    unsigned u[4] = {r.x, r.y, r.z, r.w};
#pragma unroll
    for (int i = 0; i < 4; ++i) {
        asm("v_fma_mix_f32 %0, %1, %2, %0 op_sel_hi:[1,0,0]"
            : "+v"(fs[2 * i]) : "v"(u[i]), "v"(w));
        asm("v_fma_mix_f32 %0, %1, %2, %0 op_sel:[1,0,0] op_sel_hi:[1,0,0]"
            : "+v"(fs[2 * i + 1]) : "v"(u[i]), "v"(w));
    }
}

__device__ __forceinline__ void pair_accum8(float interp[8], const __half* __restrict__ plane,
                                            float cx, float cy, float hx, float hy, int chan) {
    const int SI[13] = {2, 0, 1, 3, 4, 2, 2, 2, 2, 3, 3, 1, 1};
    const int SJ[13] = {2, 2, 2, 2, 2, 0, 1, 3, 4, 3, 1, 3, 1};

    float wx[5], wy[5];
    int colA[5], colB[5], rowA[5], rowB[5];
    float hx2 = hx + hx, hy2 = hy + hy;
    float xs[5] = {cx - hx2, cx - hx, cx, cx + hx, cx + hx2};
    float ys[5] = {cy - hy2, cy - hy, cy, cy + hy, cy + hy2};
    int colMax = 255 * 64 + chan;
#pragma unroll
    for (int k = 0; k < 5; ++k) {
        float x = fminf(fmaxf(xs[k], 0.0f), 255.0f);
        float xf = floorf(x);
        wx[k] = x - xf;
        colA[k] = (int)xf * 64 + chan;
        colB[k] = min(colA[k] + 64, colMax);
        float y = fminf(fmaxf(ys[k], 0.0f), 255.0f);
        float yf = floorf(y);
        wy[k] = y - yf;
        rowA[k] = (int)yf * (RES * 64);
        rowB[k] = min(rowA[k] + RES * 64, 255 * RES * 64);
    }

    float fs[8];
#pragma unroll
    for (int c = 0; c < 8; ++c) fs[c] = 0.0f;
    const char* base = reinterpret_cast<const char*>(plane);
#pragma unroll
    for (int s = 0; s < 13; ++s) {
        int i = SI[s], j = SJ[s];
        float wxi = wx[i], wyj = wy[j];
        float wxc = 1.0f - wxi, wyc = 1.0f - wyj;
        corner8(fs, base + (rowA[j] + colA[i]), wxc * wyc);
        corner8(fs, base + (rowA[j] + colB[i]), wxi * wyc);
        corner8(fs, base + (rowB[j] + colA[i]), wxc * wyj);
        corner8(fs, base + (rowB[j] + colB[i]), wxi * wyj);
    }
    const float inv13 = 1.0f / 13.0f;
#pragma unroll
    for (int c = 0; c < 8; ++c) interp[c] *= fs[c] * inv13;
}

// 4 lanes per point, 8 channels per lane (one 64B texel line-touch per point-corner).
__global__ __launch_bounds__(256) void wpf_main4(const float* __restrict__ ppk,
                                                 const int* __restrict__ idx_s,
                                                 const __half* __restrict__ planes, // 3 concat
                                                 float* __restrict__ out, int n, int swizzle) {
    int b = blockIdx.x;
    if (swizzle) {
        int nb = gridDim.x;
        int chunk = nb >> 3;
        b = (b & 7) * chunk + (b >> 3);
    }
    int t = b * 256 + threadIdx.x;
    int pt = t >> 2;
    int cg = t & 3;
    if (pt >= n) return;

    float4 a  = reinterpret_cast<const float4*>(ppk)[(size_t)pt * 2];
    float4 hh = reinterpret_cast<const float4*>(ppk)[(size_t)pt * 2 + 1];
    int chan = cg * 16;   // byte offset of this lane's 8 channels within 64B texel

    float interp[8];
#pragma unroll
    for (int c = 0; c < 8; ++c) interp[c] = 1.0f;

#pragma unroll 1
    for (int pr = 0; pr < 3; ++pr) {
        const __half* pl = planes + (size_t)pr * PLANE_ELEMS;
        float cx = (pr == 2) ? a.y : a.x;
        float cy = (pr == 0) ? a.y : a.z;
        float hx = (pr == 2) ? hh.y : hh.x;
        float hy = (pr == 0) ? hh.y : hh.z;
        pair_accum8(interp, pl, cx, cy, hx, hy, chan);
    }

    int oi = idx_s[pt];
    float4* o = reinterpret_cast<float4*>(out + (size_t)oi * 32 + cg * 8);
    o[0] = make_float4(interp[0], interp[1], interp[2], interp[3]);
    o[1] = make_float4(interp[4], interp[5], interp[6], interp[7]);
}

// ---------------- fallback (ws too small): direct fp32 strided path ----------------
__global__ __launch_bounds__(256) void wpf_plain(const float* __restrict__ pts,
                                                 const float* __restrict__ scales,
                                                 const float* __restrict__ p0,
                                                 const float* __restrict__ p1,
                                                 const float* __restrict__ p2,
                                                 const float* __restrict__ aabb,
                                                 float* __restrict__ out, int n) {
    const float offx[13] = {0.f, -1.f, -0.5f, 0.5f, 1.f, 0.f, 0.f, 0.f, 0.f, 0.5f, 0.5f, -0.5f, -0.5f};
    const float offy[13] = {0.f, 0.f, 0.f, 0.f, 0.f, -1.f, -0.5f, 0.5f, 1.f, 0.5f, -0.5f, 0.5f, -0.5f};
    int t = blockIdx.x * 256 + threadIdx.x;
    int pt = t >> 3;
    int cg = t & 7;
    if (pt >= n) return;
    float a00 = aabb[0], a01 = aabb[1], a02 = aabb[2];
    float a10 = aabb[3], a11 = aabb[4], a12 = aabb[5];
    float px = (pts[pt * 3 + 0] - a00) * (2.0f / (a10 - a00)) - 1.0f;
    float py = (pts[pt * 3 + 1] - a01) * (2.0f / (a11 - a01)) - 1.0f;
    float pz = (pts[pt * 3 + 2] - a02) * (2.0f / (a12 - a02)) - 1.0f;
    float scx = scales[pt * 3 + 0], scy = scales[pt * 3 + 1], scz = scales[pt * 3 + 2];
    float4 interp = make_float4(1.f, 1.f, 1.f, 1.f);
    for (int pair = 0; pair < 3; ++pair) {
        const float* plane = pair == 0 ? p0 : (pair == 1 ? p1 : p2);
        float bx = pair == 2 ? py : px;
        float by = pair == 0 ? py : pz;
        float sx = pair == 2 ? scy : scx;
        float sy = pair == 0 ? scy : scz;
        float4 featsum = make_float4(0.f, 0.f, 0.f, 0.f);
        for (int s = 0; s < 13; ++s) {
            float x = fminf(fmaxf((bx + sx * offx[s] + 1.0f) * 127.5f, 0.0f), 255.0f);
            float y = fminf(fmaxf((by + sy * offy[s] + 1.0f) * 127.5f, 0.0f), 255.0f);
            float x0f = floorf(x), y0f = floorf(y);
            float wx = x - x0f, wy = y - y0f;
            int x0 = (int)x0f, y0 = (int)y0f;
            int x1 = min(x0 + 1, RES - 1), y1 = min(y0 + 1, RES - 1);
            float w00 = (1.0f - wx) * (1.0f - wy), w10 = wx * (1.0f - wy);
            float w01 = (1.0f - wx) * wy, w11 = wx * wy;
            int c0 = cg << 2;
            for (int c = 0; c < 4; ++c) {
                const float* pl = plane + (size_t)(c0 + c) * (RES * RES);
                float f = pl[y0 * RES + x0] * w00 + pl[y0 * RES + x1] * w10 +
                          pl[y1 * RES + x0] * w01 + pl[y1 * RES + x1] * w11;
                (&featsum.x)[c] += f;
            }
        }
        const float inv13 = 1.0f / 13.0f;
        interp.x *= featsum.x * inv13;
        interp.y *= featsum.y * inv13;
        interp.z *= featsum.z * inv13;
        interp.w *= featsum.w * inv13;
    }
    reinterpret_cast<float4*>(out)[(size_t)pt * 8 + cg] = interp;
}

extern "C" void kernel_launch(void* const* d_in, const int* in_sizes, int n_in,
                              void* d_out, int out_size, void* d_ws, size_t ws_size,
                              hipStream_t stream) {
    const float* pts    = (const float*)d_in[0];
    const float* scales = (const float*)d_in[2];
    const float* p0     = (const float*)d_in[3];
    const float* p1     = (const float*)d_in[4];
    const float* p2     = (const float*)d_in[5];
    const float* aabb   = (const float*)d_in[6];
    float* out = (float*)d_out;

    int n = in_sizes[0] / 3;
    int pt_blocks = (n + 255) / 256;

    size_t planes_hbytes = (size_t)3 * PLANE_ELEMS * sizeof(__half);  // 12 MB
    size_t ppk_bytes = (size_t)n * 8 * sizeof(float);                 // 16 MB
    size_t idx_bytes = (size_t)n * sizeof(int);
    size_t key_bytes = (size_t)n * sizeof(int);
    size_t hist_bytes = (size_t)NBINS * sizeof(int);
    size_t need = planes_hbytes + ppk_bytes + idx_bytes + key_bytes + hist_bytes;

    if (ws_size >= need) {
        __half* planes_h = (__half*)d_ws;
        float*  ppk   = (float*)((char*)d_ws + planes_hbytes);
        int*    idx_s = (int*)((char*)ppk + ppk_bytes);
        int*    keys  = idx_s + n;
        int*    hist  = keys + n;

        hipMemsetAsync(hist, 0, hist_bytes, stream);
        pre_fused<<<TQ_BLOCKS + pt_blocks, 256, 0, stream>>>(p0, p1, p2, planes_h,
                                                             pts, aabb, hist, keys, n);
        scan_hist<<<1, 1024, 0, stream>>>(hist);
        scatter_pack<<<pt_blocks, 256, 0, stream>>>(pts, scales, aabb, keys, hist,
                                                    ppk, idx_s, n);
        int main_blocks = (n * 4 + 255) / 256;
        int swizzle = (main_blocks % 8 == 0) ? 1 : 0;
        wpf_main4<<<main_blocks, 256, 0, stream>>>(ppk, idx_s, planes_h, out, n, swizzle);
    } else {
        int main_blocks = (n * 8 + 255) / 256;
        wpf_plain<<<main_blocks, 256, 0, stream>>>(pts, scales, p0, p1, p2, aabb, out, n);
    }
}

// Round 6
// 405.258 us; speedup vs baseline: 1.0629x; 1.0022x over previous
//
#include <hip/hip_runtime.h>
#include <hip/hip_fp16.h>

#define RES 256
#define FEAT 32
#define PLANE_ELEMS (FEAT * RES * RES)   // 2097152, fp16 plane = 4 MB
#define NBINS 32768                      // 32^3 Morton bins
#define TQ_BLOCKS 3072                   // 3 * 262144 / 256

// ---------------- preprocessing ----------------

__device__ inline unsigned spread3(unsigned v) {
    unsigned r = 0;
    r |= (v & 1u);
    r |= (v & 2u) << 2;
    r |= (v & 4u) << 4;
    r |= (v & 8u) << 6;
    r |= (v & 16u) << 8;
    return r;
}

__device__ inline int morton_key_of(const float* __restrict__ pts,
                                    const float* __restrict__ aabb, int i) {
    float a00 = aabb[0], a01 = aabb[1], a02 = aabb[2];
    float a10 = aabb[3], a11 = aabb[4], a12 = aabb[5];
    float px = (pts[i * 3 + 0] - a00) * (2.0f / (a10 - a00)) - 1.0f;
    float py = (pts[i * 3 + 1] - a01) * (2.0f / (a11 - a01)) - 1.0f;
    float pz = (pts[i * 3 + 2] - a02) * (2.0f / (a12 - a02)) - 1.0f;
    unsigned ux = (unsigned)min(max((int)((px + 1.0f) * 16.0f), 0), 31);
    unsigned uy = (unsigned)min(max((int)((py + 1.0f) * 16.0f), 0), 31);
    unsigned uz = (unsigned)min(max((int)((pz + 1.0f) * 16.0f), 0), 31);
    return (int)(spread3(ux) | (spread3(uy) << 1) | (spread3(uz) << 2));
}

// Fused: [0, TQ_BLOCKS) transpose+quantize planes (C,H,W) fp32 -> (H,W,C) fp16;
// [TQ_BLOCKS, ...) Morton histogram.
__global__ __launch_bounds__(256) void pre_fused(const float* __restrict__ p0,
                                                 const float* __restrict__ p1,
                                                 const float* __restrict__ p2,
                                                 __half* __restrict__ outp,
                                                 const float* __restrict__ pts,
                                                 const float* __restrict__ aabb,
                                                 int* __restrict__ hist, int n) {
    if (blockIdx.x < TQ_BLOCKS) {
        int t = blockIdx.x * 256 + threadIdx.x;      // t < 3 * 262144
        int pl = t >> 18;
        int r = t & 262143;
        int cg = r & 3;
        int x = (r >> 2) & 255;
        int y = r >> 10;
        const float* in = (pl == 0 ? p0 : (pl == 1 ? p1 : p2)) + y * 256 + x;
        union { __half h[8]; uint4 v; } u;
#pragma unroll
        for (int k = 0; k < 8; ++k)
            u.h[k] = __float2half(in[(size_t)(cg * 8 + k) * 65536]);
        reinterpret_cast<uint4*>(outp)[((size_t)pl << 18) | ((size_t)((y << 8) | x) << 2) | cg] = u.v;
    } else {
        int i = (blockIdx.x - TQ_BLOCKS) * 256 + threadIdx.x;
        if (i >= n) return;
        atomicAdd(&hist[morton_key_of(pts, aabb, i)], 1);
    }
}

__global__ __launch_bounds__(1024) void scan_hist(int* __restrict__ hist) {
    __shared__ int sums[1024];
    int t = threadIdx.x;
    int base = t * 32;
    int local[32];
    int s = 0;
#pragma unroll
    for (int i = 0; i < 32; ++i) { local[i] = hist[base + i]; s += local[i]; }
    sums[t] = s;
    __syncthreads();
    for (int off = 1; off < 1024; off <<= 1) {
        int v = 0;
        if (t >= off) v = sums[t - off];
        __syncthreads();
        if (t >= off) sums[t] += v;
        __syncthreads();
    }
    int excl = (t == 0) ? 0 : sums[t - 1];
#pragma unroll
    for (int i = 0; i < 32; ++i) { hist[base + i] = excl; excl += local[i]; }
}

// Scatter sorted, pre-transformed records: [cx,cy,cz,0, hx,hy,hz,0] in pixel units.
__global__ __launch_bounds__(256) void scatter_pack(const float* __restrict__ pts,
                                                    const float* __restrict__ scales,
                                                    const float* __restrict__ aabb,
                                                    int* __restrict__ hist,
                                                    float* __restrict__ ppk,
                                                    int* __restrict__ idx_s, int n) {
    int i = blockIdx.x * 256 + threadIdx.x;
    if (i >= n) return;
    float a00 = aabb[0], a01 = aabb[1], a02 = aabb[2];
    float a10 = aabb[3], a11 = aabb[4], a12 = aabb[5];
    float px = (pts[i * 3 + 0] - a00) * (2.0f / (a10 - a00)) - 1.0f;
    float py = (pts[i * 3 + 1] - a01) * (2.0f / (a11 - a01)) - 1.0f;
    float pz = (pts[i * 3 + 2] - a02) * (2.0f / (a12 - a02)) - 1.0f;
    unsigned ux = (unsigned)min(max((int)((px + 1.0f) * 16.0f), 0), 31);
    unsigned uy = (unsigned)min(max((int)((py + 1.0f) * 16.0f), 0), 31);
    unsigned uz = (unsigned)min(max((int)((pz + 1.0f) * 16.0f), 0), 31);
    int key = (int)(spread3(ux) | (spread3(uy) << 1) | (spread3(uz) << 2));
    int pos = atomicAdd(&hist[key], 1);
    float4* o = reinterpret_cast<float4*>(ppk) + (size_t)pos * 2;
    o[0] = make_float4((px + 1.0f) * 127.5f, (py + 1.0f) * 127.5f, (pz + 1.0f) * 127.5f, 0.0f);
    o[1] = make_float4(scales[i * 3 + 0] * 63.75f, scales[i * 3 + 1] * 63.75f,
                       scales[i * 3 + 2] * 63.75f, 0.0f);
    idx_s[pos] = i;
}

// ---------------- main kernel ----------------

// 8 fp16 channels MAC'd into 8 fp32 accumulators with v_fma_mix_f32.
__device__ __forceinline__ void mac8(float fs[8], const uint4& r, float w) {
    unsigned u[4] = {r.x, r.y, r.z, r.w};
#pragma unroll
    for (int i = 0; i < 4; ++i) {
        asm("v_fma_mix_f32 %0, %1, %2, %0 op_sel_hi:[1,0,0]"
            : "+v"(fs[2 * i]) : "v"(u[i]), "v"(w));
        asm("v_fma_mix_f32 %0, %1, %2, %0 op_sel:[1,0,0] op_sel_hi:[1,0,0]"
            : "+v"(fs[2 * i + 1]) : "v"(u[i]), "v"(w));
    }
}

__device__ __forceinline__ void pair_accum8(float interp[8], const __half* __restrict__ plane,
                                            float cx, float cy, float hx, float hy, int chan) {
    const int SI[13] = {2, 0, 1, 3, 4, 2, 2, 2, 2, 3, 3, 1, 1};
    const int SJ[13] = {2, 2, 2, 2, 2, 0, 1, 3, 4, 3, 1, 3, 1};

    float wx[5], wy[5];
    int colA[5], colB[5], rowA[5], rowB[5];
    float hx2 = hx + hx, hy2 = hy + hy;
    float xs[5] = {cx - hx2, cx - hx, cx, cx + hx, cx + hx2};
    float ys[5] = {cy - hy2, cy - hy, cy, cy + hy, cy + hy2};
    int colMax = 255 * 64 + chan;
#pragma unroll
    for (int k = 0; k < 5; ++k) {
        float x = fminf(fmaxf(xs[k], 0.0f), 255.0f);
        float xf = floorf(x);
        wx[k] = x - xf;
        colA[k] = (int)xf * 64 + chan;
        colB[k] = min(colA[k] + 64, colMax);
        float y = fminf(fmaxf(ys[k], 0.0f), 255.0f);
        float yf = floorf(y);
        wy[k] = y - yf;
        rowA[k] = (int)yf * (RES * 64);
        rowB[k] = min(rowA[k] + RES * 64, 255 * RES * 64);
    }

    float fs[8];
#pragma unroll
    for (int c = 0; c < 8; ++c) fs[c] = 0.0f;
    const char* base = reinterpret_cast<const char*>(plane);
#pragma unroll
    for (int s = 0; s < 13; ++s) {
        int i = SI[s], j = SJ[s];
        float wxi = wx[i], wyj = wy[j];
        float wxc = 1.0f - wxi, wyc = 1.0f - wyj;
        // Batch all 4 corner loads before consuming (explicit MLP).
        uint4 r00 = *reinterpret_cast<const uint4*>(base + (rowA[j] + colA[i]));
        uint4 r10 = *reinterpret_cast<const uint4*>(base + (rowA[j] + colB[i]));
        uint4 r01 = *reinterpret_cast<const uint4*>(base + (rowB[j] + colA[i]));
        uint4 r11 = *reinterpret_cast<const uint4*>(base + (rowB[j] + colB[i]));
        mac8(fs, r00, wxc * wyc);
        mac8(fs, r10, wxi * wyc);
        mac8(fs, r01, wxc * wyj);
        mac8(fs, r11, wxi * wyj);
    }
    const float inv13 = 1.0f / 13.0f;
#pragma unroll
    for (int c = 0; c < 8; ++c) interp[c] *= fs[c] * inv13;
}

// 4 lanes per point, 8 channels per lane (one 64B texel line-touch per point-corner).
// 48KB LDS pad caps residency at 3 blocks/CU (12 waves): keeps the per-CU gather
// working set inside L1 and frees VGPR budget for load batching.
__global__ __launch_bounds__(256) void wpf_main4(const float* __restrict__ ppk,
                                                 const int* __restrict__ idx_s,
                                                 const __half* __restrict__ planes, // 3 concat
                                                 float* __restrict__ out, int n, int swizzle) {
    __shared__ char occ_pad[49152];
    if (n == -2147483647) occ_pad[threadIdx.x & 255] = 1;   // opaque: keeps LDS alive

    int b = blockIdx.x;
    if (swizzle) {
        int nb = gridDim.x;
        int chunk = nb >> 3;
        b = (b & 7) * chunk + (b >> 3);
    }
    int t = b * 256 + threadIdx.x;
    int pt = t >> 2;
    int cg = t & 3;
    if (pt >= n) return;

    float4 a  = reinterpret_cast<const float4*>(ppk)[(size_t)pt * 2];
    float4 hh = reinterpret_cast<const float4*>(ppk)[(size_t)pt * 2 + 1];
    int chan = cg * 16;   // byte offset of this lane's 8 channels within 64B texel

    float interp[8];
#pragma unroll
    for (int c = 0; c < 8; ++c) interp[c] = 1.0f;

#pragma unroll 1
    for (int pr = 0; pr < 3; ++pr) {
        const __half* pl = planes + (size_t)pr * PLANE_ELEMS;
        float cx = (pr == 2) ? a.y : a.x;
        float cy = (pr == 0) ? a.y : a.z;
        float hx = (pr == 2) ? hh.y : hh.x;
        float hy = (pr == 0) ? hh.y : hh.z;
        pair_accum8(interp, pl, cx, cy, hx, hy, chan);
    }

    int oi = idx_s[pt];
    float4* o = reinterpret_cast<float4*>(out + (size_t)oi * 32 + cg * 8);
    o[0] = make_float4(interp[0], interp[1], interp[2], interp[3]);
    o[1] = make_float4(interp[4], interp[5], interp[6], interp[7]);
}

// ---------------- fallback (ws too small): direct fp32 strided path ----------------
__global__ __launch_bounds__(256) void wpf_plain(const float* __restrict__ pts,
                                                 const float* __restrict__ scales,
                                                 const float* __restrict__ p0,
                                                 const float* __restrict__ p1,
                                                 const float* __restrict__ p2,
                                                 const float* __restrict__ aabb,
                                                 float* __restrict__ out, int n) {
    const float offx[13] = {0.f, -1.f, -0.5f, 0.5f, 1.f, 0.f, 0.f, 0.f, 0.f, 0.5f, 0.5f, -0.5f, -0.5f};
    const float offy[13] = {0.f, 0.f, 0.f, 0.f, 0.f, -1.f, -0.5f, 0.5f, 1.f, 0.5f, -0.5f, 0.5f, -0.5f};
    int t = blockIdx.x * 256 + threadIdx.x;
    int pt = t >> 3;
    int cg = t & 7;
    if (pt >= n) return;
    float a00 = aabb[0], a01 = aabb[1], a02 = aabb[2];
    float a10 = aabb[3], a11 = aabb[4], a12 = aabb[5];
    float px = (pts[pt * 3 + 0] - a00) * (2.0f / (a10 - a00)) - 1.0f;
    float py = (pts[pt * 3 + 1] - a01) * (2.0f / (a11 - a01)) - 1.0f;
    float pz = (pts[pt * 3 + 2] - a02) * (2.0f / (a12 - a02)) - 1.0f;
    float scx = scales[pt * 3 + 0], scy = scales[pt * 3 + 1], scz = scales[pt * 3 + 2];
    float4 interp = make_float4(1.f, 1.f, 1.f, 1.f);
    for (int pair = 0; pair < 3; ++pair) {
        const float* plane = pair == 0 ? p0 : (pair == 1 ? p1 : p2);
        float bx = pair == 2 ? py : px;
        float by = pair == 0 ? py : pz;
        float sx = pair == 2 ? scy : scx;
        float sy = pair == 0 ? scy : scz;
        float4 featsum = make_float4(0.f, 0.f, 0.f, 0.f);
        for (int s = 0; s < 13; ++s) {
            float x = fminf(fmaxf((bx + sx * offx[s] + 1.0f) * 127.5f, 0.0f), 255.0f);
            float y = fminf(fmaxf((by + sy * offy[s] + 1.0f) * 127.5f, 0.0f), 255.0f);
            float x0f = floorf(x), y0f = floorf(y);
            float wx = x - x0f, wy = y - y0f;
            int x0 = (int)x0f, y0 = (int)y0f;
            int x1 = min(x0 + 1, RES - 1), y1 = min(y0 + 1, RES - 1);
            float w00 = (1.0f - wx) * (1.0f - wy), w10 = wx * (1.0f - wy);
            float w01 = (1.0f - wx) * wy, w11 = wx * wy;
            int c0 = cg << 2;
            for (int c = 0; c < 4; ++c) {
                const float* pl = plane + (size_t)(c0 + c) * (RES * RES);
                float f = pl[y0 * RES + x0] * w00 + pl[y0 * RES + x1] * w10 +
                          pl[y1 * RES + x0] * w01 + pl[y1 * RES + x1] * w11;
                (&featsum.x)[c] += f;
            }
        }
        const float inv13 = 1.0f / 13.0f;
        interp.x *= featsum.x * inv13;
        interp.y *= featsum.y * inv13;
        interp.z *= featsum.z * inv13;
        interp.w *= featsum.w * inv13;
    }
    reinterpret_cast<float4*>(out)[(size_t)pt * 8 + cg] = interp;
}

extern "C" void kernel_launch(void* const* d_in, const int* in_sizes, int n_in,
                              void* d_out, int out_size, void* d_ws, size_t ws_size,
                              hipStream_t stream) {
    const float* pts    = (const float*)d_in[0];
    const float* scales = (const float*)d_in[2];
    const float* p0     = (const float*)d_in[3];
    const float* p1     = (const float*)d_in[4];
    const float* p2     = (const float*)d_in[5];
    const float* aabb   = (const float*)d_in[6];
    float* out = (float*)d_out;

    int n = in_sizes[0] / 3;
    int pt_blocks = (n + 255) / 256;

    size_t planes_hbytes = (size_t)3 * PLANE_ELEMS * sizeof(__half);  // 12 MB
    size_t ppk_bytes = (size_t)n * 8 * sizeof(float);                 // 16 MB
    size_t idx_bytes = (size_t)n * sizeof(int);
    size_t hist_bytes = (size_t)NBINS * sizeof(int);
    size_t need = planes_hbytes + ppk_bytes + idx_bytes + hist_bytes;

    if (ws_size >= need) {
        __half* planes_h = (__half*)d_ws;
        float*  ppk   = (float*)((char*)d_ws + planes_hbytes);
        int*    idx_s = (int*)((char*)ppk + ppk_bytes);
        int*    hist  = idx_s + n;

        hipMemsetAsync(hist, 0, hist_bytes, stream);
        pre_fused<<<TQ_BLOCKS + pt_blocks, 256, 0, stream>>>(p0, p1, p2, planes_h,
                                                             pts, aabb, hist, n);
        scan_hist<<<1, 1024, 0, stream>>>(hist);
        scatter_pack<<<pt_blocks, 256, 0, stream>>>(pts, scales, aabb, hist,
                                                    ppk, idx_s, n);
        int main_blocks = (n * 4 + 255) / 256;
        int swizzle = (main_blocks % 8 == 0) ? 1 : 0;
        wpf_main4<<<main_blocks, 256, 0, stream>>>(ppk, idx_s, planes_h, out, n, swizzle);
    } else {
        int main_blocks = (n * 8 + 255) / 256;
        wpf_plain<<<main_blocks, 256, 0, stream>>>(pts, scales, p0, p1, p2, aabb, out, n);
    }
}

// Round 7
// 378.948 us; speedup vs baseline: 1.1367x; 1.0694x over previous
//
#include <hip/hip_runtime.h>
#include <hip/hip_fp16.h>

#define RES 256
#define FEAT 32
#define PLANE_ELEMS (FEAT * RES * RES)   // 2097152, fp16 plane = 4 MB
#define NBINS 32768                      // 32^3 Morton bins
#define TQ_BLOCKS 3072                   // 3 * 262144 / 256

// ---------------- preprocessing ----------------

__device__ inline unsigned spread3(unsigned v) {
    unsigned r = 0;
    r |= (v & 1u);
    r |= (v & 2u) << 2;
    r |= (v & 4u) << 4;
    r |= (v & 8u) << 6;
    r |= (v & 16u) << 8;
    return r;
}

__device__ inline int morton_key_of(const float* __restrict__ pts,
                                    const float* __restrict__ aabb, int i) {
    float a00 = aabb[0], a01 = aabb[1], a02 = aabb[2];
    float a10 = aabb[3], a11 = aabb[4], a12 = aabb[5];
    float px = (pts[i * 3 + 0] - a00) * (2.0f / (a10 - a00)) - 1.0f;
    float py = (pts[i * 3 + 1] - a01) * (2.0f / (a11 - a01)) - 1.0f;
    float pz = (pts[i * 3 + 2] - a02) * (2.0f / (a12 - a02)) - 1.0f;
    unsigned ux = (unsigned)min(max((int)((px + 1.0f) * 16.0f), 0), 31);
    unsigned uy = (unsigned)min(max((int)((py + 1.0f) * 16.0f), 0), 31);
    unsigned uz = (unsigned)min(max((int)((pz + 1.0f) * 16.0f), 0), 31);
    return (int)(spread3(ux) | (spread3(uy) << 1) | (spread3(uz) << 2));
}

// Fused: [0, TQ_BLOCKS) transpose+quantize planes (C,H,W) fp32 -> (H,W,C) fp16;
// [TQ_BLOCKS, ...) Morton histogram.
__global__ __launch_bounds__(256) void pre_fused(const float* __restrict__ p0,
                                                 const float* __restrict__ p1,
                                                 const float* __restrict__ p2,
                                                 __half* __restrict__ outp,
                                                 const float* __restrict__ pts,
                                                 const float* __restrict__ aabb,
                                                 int* __restrict__ hist, int n) {
    if (blockIdx.x < TQ_BLOCKS) {
        int t = blockIdx.x * 256 + threadIdx.x;      // t < 3 * 262144
        int pl = t >> 18;
        int r = t & 262143;
        int cg = r & 3;
        int x = (r >> 2) & 255;
        int y = r >> 10;
        const float* in = (pl == 0 ? p0 : (pl == 1 ? p1 : p2)) + y * 256 + x;
        union { __half h[8]; uint4 v; } u;
#pragma unroll
        for (int k = 0; k < 8; ++k)
            u.h[k] = __float2half(in[(size_t)(cg * 8 + k) * 65536]);
        reinterpret_cast<uint4*>(outp)[((size_t)pl << 18) | ((size_t)((y << 8) | x) << 2) | cg] = u.v;
    } else {
        int i = (blockIdx.x - TQ_BLOCKS) * 256 + threadIdx.x;
        if (i >= n) return;
        atomicAdd(&hist[morton_key_of(pts, aabb, i)], 1);
    }
}

__global__ __launch_bounds__(1024) void scan_hist(int* __restrict__ hist) {
    __shared__ int sums[1024];
    int t = threadIdx.x;
    int base = t * 32;
    int local[32];
    int s = 0;
#pragma unroll
    for (int i = 0; i < 32; ++i) { local[i] = hist[base + i]; s += local[i]; }
    sums[t] = s;
    __syncthreads();
    for (int off = 1; off < 1024; off <<= 1) {
        int v = 0;
        if (t >= off) v = sums[t - off];
        __syncthreads();
        if (t >= off) sums[t] += v;
        __syncthreads();
    }
    int excl = (t == 0) ? 0 : sums[t - 1];
#pragma unroll
    for (int i = 0; i < 32; ++i) { hist[base + i] = excl; excl += local[i]; }
}

// Scatter sorted, pre-transformed records: [cx,cy,cz,0, hx,hy,hz,0] in pixel units.
__global__ __launch_bounds__(256) void scatter_pack(const float* __restrict__ pts,
                                                    const float* __restrict__ scales,
                                                    const float* __restrict__ aabb,
                                                    int* __restrict__ hist,
                                                    float* __restrict__ ppk,
                                                    int* __restrict__ idx_s, int n) {
    int i = blockIdx.x * 256 + threadIdx.x;
    if (i >= n) return;
    float a00 = aabb[0], a01 = aabb[1], a02 = aabb[2];
    float a10 = aabb[3], a11 = aabb[4], a12 = aabb[5];
    float px = (pts[i * 3 + 0] - a00) * (2.0f / (a10 - a00)) - 1.0f;
    float py = (pts[i * 3 + 1] - a01) * (2.0f / (a11 - a01)) - 1.0f;
    float pz = (pts[i * 3 + 2] - a02) * (2.0f / (a12 - a02)) - 1.0f;
    unsigned ux = (unsigned)min(max((int)((px + 1.0f) * 16.0f), 0), 31);
    unsigned uy = (unsigned)min(max((int)((py + 1.0f) * 16.0f), 0), 31);
    unsigned uz = (unsigned)min(max((int)((pz + 1.0f) * 16.0f), 0), 31);
    int key = (int)(spread3(ux) | (spread3(uy) << 1) | (spread3(uz) << 2));
    int pos = atomicAdd(&hist[key], 1);
    float4* o = reinterpret_cast<float4*>(ppk) + (size_t)pos * 2;
    o[0] = make_float4((px + 1.0f) * 127.5f, (py + 1.0f) * 127.5f, (pz + 1.0f) * 127.5f, 0.0f);
    o[1] = make_float4(scales[i * 3 + 0] * 63.75f, scales[i * 3 + 1] * 63.75f,
                       scales[i * 3 + 2] * 63.75f, 0.0f);
    idx_s[pos] = i;
}

// ---------------- main kernel ----------------

// 8 fp16 channels MAC'd into 8 fp32 accumulators with v_fma_mix_f32.
__device__ __forceinline__ void mac8(float fs[8], const uint4& r, float w) {
    unsigned u[4] = {r.x, r.y, r.z, r.w};
#pragma unroll
    for (int i = 0; i < 4; ++i) {
        asm("v_fma_mix_f32 %0, %1, %2, %0 op_sel_hi:[1,0,0]"
            : "+v"(fs[2 * i]) : "v"(u[i]), "v"(w));
        asm("v_fma_mix_f32 %0, %1, %2, %0 op_sel:[1,0,0] op_sel_hi:[1,0,0]"
            : "+v"(fs[2 * i + 1]) : "v"(u[i]), "v"(w));
    }
}

__device__ __forceinline__ void pair_accum8(float interp[8], const __half* __restrict__ plane,
                                            float cx, float cy, float hx, float hy, int chan) {
    const int SI[13] = {2, 0, 1, 3, 4, 2, 2, 2, 2, 3, 3, 1, 1};
    const int SJ[13] = {2, 2, 2, 2, 2, 0, 1, 3, 4, 3, 1, 3, 1};

    float wx[5], wy[5];
    int colA[5], colB[5], rowA[5], rowB[5];
    float hx2 = hx + hx, hy2 = hy + hy;
    float xs[5] = {cx - hx2, cx - hx, cx, cx + hx, cx + hx2};
    float ys[5] = {cy - hy2, cy - hy, cy, cy + hy, cy + hy2};
    int colMax = 255 * 64 + chan;
#pragma unroll
    for (int k = 0; k < 5; ++k) {
        float x = fminf(fmaxf(xs[k], 0.0f), 255.0f);
        float xf = floorf(x);
        wx[k] = x - xf;
        colA[k] = (int)xf * 64 + chan;
        colB[k] = min(colA[k] + 64, colMax);
        float y = fminf(fmaxf(ys[k], 0.0f), 255.0f);
        float yf = floorf(y);
        wy[k] = y - yf;
        rowA[k] = (int)yf * (RES * 64);
        rowB[k] = min(rowA[k] + RES * 64, 255 * RES * 64);
    }

    float fs[8];
#pragma unroll
    for (int c = 0; c < 8; ++c) fs[c] = 0.0f;
    const char* base = reinterpret_cast<const char*>(plane);
#pragma unroll
    for (int s = 0; s < 13; ++s) {
        int i = SI[s], j = SJ[s];
        float wxi = wx[i], wyj = wy[j];
        float wxc = 1.0f - wxi, wyc = 1.0f - wyj;
        // Batch all 4 corner loads before consuming (explicit MLP).
        uint4 r00 = *reinterpret_cast<const uint4*>(base + (rowA[j] + colA[i]));
        uint4 r10 = *reinterpret_cast<const uint4*>(base + (rowA[j] + colB[i]));
        uint4 r01 = *reinterpret_cast<const uint4*>(base + (rowB[j] + colA[i]));
        uint4 r11 = *reinterpret_cast<const uint4*>(base + (rowB[j] + colB[i]));
        mac8(fs, r00, wxc * wyc);
        mac8(fs, r10, wxi * wyc);
        mac8(fs, r01, wxc * wyj);
        mac8(fs, r11, wxi * wyj);
    }
    const float inv13 = 1.0f / 13.0f;
#pragma unroll
    for (int c = 0; c < 8; ++c) interp[c] *= fs[c] * inv13;
}

// 4 lanes per point, 8 channels per lane (one 64B texel line-touch per point-corner).
// 48KB LDS pad caps residency at 3 blocks/CU (12 waves): keeps the per-CU gather
// working set L1-friendly and lets the register allocator target 3 waves/SIMD
// (~170 VGPR) so the 4-corner load batch is actually in flight.
// Volatile store: compiler cannot DCE the LDS allocation (round-6 lesson).
__global__ __launch_bounds__(256) void wpf_main4(const float* __restrict__ ppk,
                                                 const int* __restrict__ idx_s,
                                                 const __half* __restrict__ planes, // 3 concat
                                                 float* __restrict__ out, int n, int swizzle) {
    __shared__ char occ_pad[49152];
    volatile char* vp = occ_pad;
    vp[threadIdx.x] = 0;

    int b = blockIdx.x;
    if (swizzle) {
        int nb = gridDim.x;
        int chunk = nb >> 3;
        b = (b & 7) * chunk + (b >> 3);
    }
    int t = b * 256 + threadIdx.x;
    int pt = t >> 2;
    int cg = t & 3;
    if (pt >= n) return;

    float4 a  = reinterpret_cast<const float4*>(ppk)[(size_t)pt * 2];
    float4 hh = reinterpret_cast<const float4*>(ppk)[(size_t)pt * 2 + 1];
    int oi = idx_s[pt];   // hoisted: independent load, overlaps with gather setup
    int chan = cg * 16;   // byte offset of this lane's 8 channels within 64B texel

    float interp[8];
#pragma unroll
    for (int c = 0; c < 8; ++c) interp[c] = 1.0f;

#pragma unroll 1
    for (int pr = 0; pr < 3; ++pr) {
        const __half* pl = planes + (size_t)pr * PLANE_ELEMS;
        float cx = (pr == 2) ? a.y : a.x;
        float cy = (pr == 0) ? a.y : a.z;
        float hx = (pr == 2) ? hh.y : hh.x;
        float hy = (pr == 0) ? hh.y : hh.z;
        pair_accum8(interp, pl, cx, cy, hx, hy, chan);
    }

    float4* o = reinterpret_cast<float4*>(out + (size_t)oi * 32 + cg * 8);
    o[0] = make_float4(interp[0], interp[1], interp[2], interp[3]);
    o[1] = make_float4(interp[4], interp[5], interp[6], interp[7]);
}

// ---------------- fallback (ws too small): direct fp32 strided path ----------------
__global__ __launch_bounds__(256) void wpf_plain(const float* __restrict__ pts,
                                                 const float* __restrict__ scales,
                                                 const float* __restrict__ p0,
                                                 const float* __restrict__ p1,
                                                 const float* __restrict__ p2,
                                                 const float* __restrict__ aabb,
                                                 float* __restrict__ out, int n) {
    const float offx[13] = {0.f, -1.f, -0.5f, 0.5f, 1.f, 0.f, 0.f, 0.f, 0.f, 0.5f, 0.5f, -0.5f, -0.5f};
    const float offy[13] = {0.f, 0.f, 0.f, 0.f, 0.f, -1.f, -0.5f, 0.5f, 1.f, 0.5f, -0.5f, 0.5f, -0.5f};
    int t = blockIdx.x * 256 + threadIdx.x;
    int pt = t >> 3;
    int cg = t & 7;
    if (pt >= n) return;
    float a00 = aabb[0], a01 = aabb[1], a02 = aabb[2];
    float a10 = aabb[3], a11 = aabb[4], a12 = aabb[5];
    float px = (pts[pt * 3 + 0] - a00) * (2.0f / (a10 - a00)) - 1.0f;
    float py = (pts[pt * 3 + 1] - a01) * (2.0f / (a11 - a01)) - 1.0f;
    float pz = (pts[pt * 3 + 2] - a02) * (2.0f / (a12 - a02)) - 1.0f;
    float scx = scales[pt * 3 + 0], scy = scales[pt * 3 + 1], scz = scales[pt * 3 + 2];
    float4 interp = make_float4(1.f, 1.f, 1.f, 1.f);
    for (int pair = 0; pair < 3; ++pair) {
        const float* plane = pair == 0 ? p0 : (pair == 1 ? p1 : p2);
        float bx = pair == 2 ? py : px;
        float by = pair == 0 ? py : pz;
        float sx = pair == 2 ? scy : scx;
        float sy = pair == 0 ? scy : scz;
        float4 featsum = make_float4(0.f, 0.f, 0.f, 0.f);
        for (int s = 0; s < 13; ++s) {
            float x = fminf(fmaxf((bx + sx * offx[s] + 1.0f) * 127.5f, 0.0f), 255.0f);
            float y = fminf(fmaxf((by + sy * offy[s] + 1.0f) * 127.5f, 0.0f), 255.0f);
            float x0f = floorf(x), y0f = floorf(y);
            float wx = x - x0f, wy = y - y0f;
            int x0 = (int)x0f, y0 = (int)y0f;
            int x1 = min(x0 + 1, RES - 1), y1 = min(y0 + 1, RES - 1);
            float w00 = (1.0f - wx) * (1.0f - wy), w10 = wx * (1.0f - wy);
            float w01 = (1.0f - wx) * wy, w11 = wx * wy;
            int c0 = cg << 2;
            for (int c = 0; c < 4; ++c) {
                const float* pl = plane + (size_t)(c0 + c) * (RES * RES);
                float f = pl[y0 * RES + x0] * w00 + pl[y0 * RES + x1] * w10 +
                          pl[y1 * RES + x0] * w01 + pl[y1 * RES + x1] * w11;
                (&featsum.x)[c] += f;
            }
        }
        const float inv13 = 1.0f / 13.0f;
        interp.x *= featsum.x * inv13;
        interp.y *= featsum.y * inv13;
        interp.z *= featsum.z * inv13;
        interp.w *= featsum.w * inv13;
    }
    reinterpret_cast<float4*>(out)[(size_t)pt * 8 + cg] = interp;
}

extern "C" void kernel_launch(void* const* d_in, const int* in_sizes, int n_in,
                              void* d_out, int out_size, void* d_ws, size_t ws_size,
                              hipStream_t stream) {
    const float* pts    = (const float*)d_in[0];
    const float* scales = (const float*)d_in[2];
    const float* p0     = (const float*)d_in[3];
    const float* p1     = (const float*)d_in[4];
    const float* p2     = (const float*)d_in[5];
    const float* aabb   = (const float*)d_in[6];
    float* out = (float*)d_out;

    int n = in_sizes[0] / 3;
    int pt_blocks = (n + 255) / 256;

    size_t planes_hbytes = (size_t)3 * PLANE_ELEMS * sizeof(__half);  // 12 MB
    size_t ppk_bytes = (size_t)n * 8 * sizeof(float);                 // 16 MB
    size_t idx_bytes = (size_t)n * sizeof(int);
    size_t hist_bytes = (size_t)NBINS * sizeof(int);
    size_t need = planes_hbytes + ppk_bytes + idx_bytes + hist_bytes;

    if (ws_size >= need) {
        __half* planes_h = (__half*)d_ws;
        float*  ppk   = (float*)((char*)d_ws + planes_hbytes);
        int*    idx_s = (int*)((char*)ppk + ppk_bytes);
        int*    hist  = idx_s + n;

        hipMemsetAsync(hist, 0, hist_bytes, stream);
        pre_fused<<<TQ_BLOCKS + pt_blocks, 256, 0, stream>>>(p0, p1, p2, planes_h,
                                                             pts, aabb, hist, n);
        scan_hist<<<1, 1024, 0, stream>>>(hist);
        scatter_pack<<<pt_blocks, 256, 0, stream>>>(pts, scales, aabb, hist,
                                                    ppk, idx_s, n);
        int main_blocks = (n * 4 + 255) / 256;
        int swizzle = (main_blocks % 8 == 0) ? 1 : 0;
        wpf_main4<<<main_blocks, 256, 0, stream>>>(ppk, idx_s, planes_h, out, n, swizzle);
    } else {
        int main_blocks = (n * 8 + 255) / 256;
        wpf_plain<<<main_blocks, 256, 0, stream>>>(pts, scales, p0, p1, p2, aabb, out, n);
    }
}